// Round 4
// baseline (842.705 us; speedup 1.0000x reference)
//
#include <hip/hip_runtime.h>
#include <hip/hip_fp16.h>

#define NUM_USERS 100000
#define NN        200000          // N = users + items
#define DD        64
#define EE        3200000
#define SCAN_CHUNK 2048
#define NB_SCAN   ((NN + SCAN_CHUNK - 1) / SCAN_CHUNK)   // 98 blocks

typedef _Float16 half8 __attribute__((ext_vector_type(8)));
typedef _Float16 half4 __attribute__((ext_vector_type(4)));
typedef float    f32x4 __attribute__((ext_vector_type(4)));

// ---------------------------------------------------------------------------
// CSR build
// ---------------------------------------------------------------------------
__global__ __launch_bounds__(256) void hist_kernel(
    const int* __restrict__ ei, int* __restrict__ counts)
{
    const int e = blockIdx.x * 256 + threadIdx.x;
    if (e < EE) atomicAdd(&counts[ei[EE + e]], 1);
}

__global__ __launch_bounds__(256) void scan_partials_kernel(
    const int* __restrict__ counts, int* __restrict__ bsum)
{
    __shared__ int s[256];
    const int t = threadIdx.x;
    int sum = 0;
    for (int i = t; i < SCAN_CHUNK; i += 256) {
        const int idx = blockIdx.x * SCAN_CHUNK + i;
        sum += (idx < NN) ? counts[idx] : 0;
    }
    s[t] = sum; __syncthreads();
    for (int off = 128; off > 0; off >>= 1) {
        if (t < off) s[t] += s[t + off];
        __syncthreads();
    }
    if (t == 0) bsum[blockIdx.x] = s[0];
}

__global__ __launch_bounds__(128) void scan_top_kernel(int* __restrict__ bsum)
{
    __shared__ int s[128];
    const int t = threadIdx.x;
    const int v = (t < NB_SCAN) ? bsum[t] : 0;
    s[t] = v; __syncthreads();
    for (int off = 1; off < 128; off <<= 1) {
        int add = (t >= off) ? s[t - off] : 0;
        __syncthreads();
        s[t] += add;
        __syncthreads();
    }
    if (t < NB_SCAN) bsum[t] = s[t] - v;   // exclusive
}

__global__ __launch_bounds__(256) void scan_write_kernel(
    const int* __restrict__ counts, const int* __restrict__ bsum,
    int* __restrict__ row_ptr, int* __restrict__ ofs)
{
    __shared__ int s[256];
    const int t    = threadIdx.x;
    const int base = blockIdx.x * SCAN_CHUNK + t * 8;
    int c[8], ex[8], run = 0;
#pragma unroll
    for (int j = 0; j < 8; ++j) {
        const int idx = base + j;
        c[j] = (idx < NN) ? counts[idx] : 0;
        ex[j] = run; run += c[j];
    }
    s[t] = run; __syncthreads();
    for (int off = 1; off < 256; off <<= 1) {
        int add = (t >= off) ? s[t - off] : 0;
        __syncthreads();
        s[t] += add;
        __syncthreads();
    }
    const int thread_base = bsum[blockIdx.x] + s[t] - run;
#pragma unroll
    for (int j = 0; j < 8; ++j) {
        const int idx = base + j;
        if (idx < NN) {
            const int v = thread_base + ex[j];
            row_ptr[idx] = v;
            ofs[idx]     = v;
        }
    }
    if (blockIdx.x == 0 && t == 0) row_ptr[NN] = EE;
}

// Scatter edges into dst-sorted order. KEY CHANGE vs round 3: the scattered
// 8 B write goes out as a 64-bit far atomicExch (global_atomic_swap_x2,
// performed at the coherence point, 8 B exact) instead of a plain store
// (which write-allocates a full 64 B line per edge -> 198 MB WRITE_SIZE).
__global__ __launch_bounds__(256) void reorder_kernel(
    const int* __restrict__ ei, const float* __restrict__ ew,
    int* __restrict__ ofs, int2* __restrict__ edges)
{
    const int e = blockIdx.x * 256 + threadIdx.x;
    if (e >= EE) return;
    const int   src = ei[e];
    const int   dst = ei[EE + e];
    const float w   = ew[e];
    const int pos = atomicAdd(&ofs[dst], 1);
    const unsigned long long packed =
        ((unsigned long long)(unsigned)__float_as_int(w) << 32) | (unsigned)src;
    atomicExch((unsigned long long*)&edges[pos], packed);   // 8 B, no line alloc
}

// ---------------------------------------------------------------------------
// fp32 embeddings -> fp16 gather table xh [N][64]
// ---------------------------------------------------------------------------
__global__ __launch_bounds__(256) void convert_x_kernel(
    const float* __restrict__ xu, const float* __restrict__ xi,
    _Float16* __restrict__ xh)
{
    const int i = blockIdx.x * 256 + threadIdx.x;      // one float4 each
    if (i >= NN * DD / 4) return;
    const float4 v = (i < NUM_USERS * DD / 4)
                       ? ((const float4*)xu)[i]
                       : ((const float4*)xi)[i - NUM_USERS * DD / 4];
    half4 o; o[0] = (_Float16)v.x; o[1] = (_Float16)v.y;
             o[2] = (_Float16)v.z; o[3] = (_Float16)v.w;
    ((half4*)xh)[i] = o;
}

// W [k][n] fp32 -> Wt [n][k] fp16
__global__ __launch_bounds__(256) void convert_w_kernel(
    const float* __restrict__ W1, const float* __restrict__ W2,
    _Float16* __restrict__ Wt)
{
    const int idx = blockIdx.x * 256 + threadIdx.x;    // 2*4096
    if (idx >= 2 * DD * DD) return;
    const int mat = idx >> 12, rem = idx & 4095, k = rem >> 6, n = rem & 63;
    const float* W = mat ? W2 : W1;
    Wt[mat * DD * DD + n * DD + k] = (_Float16)W[k * DD + n];
}

// ---------------------------------------------------------------------------
// Aggregation: one wave per node, lane d = dim d. DS-free.
//   u[node] = 0.5 * ( xh[node] + sum_e w_e * xh[src_e] )   (fp32 acc, fp16 out)
// ---------------------------------------------------------------------------
__global__ __launch_bounds__(256) void aggregate_kernel(
    const int2* __restrict__ edges, const int* __restrict__ row_ptr,
    const _Float16* __restrict__ xh, _Float16* __restrict__ u)
{
    const int node = blockIdx.x * 4 + (threadIdx.x >> 6);   // grid covers NN exactly
    const int lane = threadIdx.x & 63;

    float acc = (float)xh[(size_t)node * DD + lane];        // residual term
    const int beg = row_ptr[node];
    const int end = row_ptr[node + 1];
    int e = beg;
    for (; e + 4 <= end; e += 4) {                          // 4 gathers in flight
        const int2 p0 = edges[e + 0];
        const int2 p1 = edges[e + 1];
        const int2 p2 = edges[e + 2];
        const int2 p3 = edges[e + 3];
        const float v0 = (float)xh[(size_t)p0.x * DD + lane];
        const float v1 = (float)xh[(size_t)p1.x * DD + lane];
        const float v2 = (float)xh[(size_t)p2.x * DD + lane];
        const float v3 = (float)xh[(size_t)p3.x * DD + lane];
        acc = fmaf(__int_as_float(p0.y), v0, acc);
        acc = fmaf(__int_as_float(p1.y), v1, acc);
        acc = fmaf(__int_as_float(p2.y), v2, acc);
        acc = fmaf(__int_as_float(p3.y), v3, acc);
    }
    for (; e < end; ++e) {
        const int2 p = edges[e];
        acc = fmaf(__int_as_float(p.y), (float)xh[(size_t)p.x * DD + lane], acc);
    }
    u[(size_t)node * DD + lane] = (_Float16)(acc * 0.5f);
}

// ---------------------------------------------------------------------------
// GEMM: out[N,64] = u[N,64] @ W[64,64] + b, via mfma_f32_16x16x32_f16.
// ---------------------------------------------------------------------------
template<bool HALF_OUT>
__global__ __launch_bounds__(256) void gemm64_kernel(
    const _Float16* __restrict__ u, const _Float16* __restrict__ Wt,
    const float* __restrict__ bias, void* __restrict__ outp)
{
    const int wid  = blockIdx.x * 4 + (threadIdx.x >> 6);   // 0..12499
    const int lane = threadIdx.x & 63;
    const int m    = lane & 15;
    const int quad = lane >> 4;
    const size_t rowbase = (size_t)wid * 16;

    half8 bf[4][2];                                         // [col tile][k half]
#pragma unroll
    for (int c = 0; c < 4; ++c)
#pragma unroll
        for (int h = 0; h < 2; ++h)
            bf[c][h] = *(const half8*)(Wt + (size_t)(c * 16 + m) * DD + h * 32 + quad * 8);

    const half8 a0 = *(const half8*)(u + (rowbase + m) * DD +  0 + quad * 8);
    const half8 a1 = *(const half8*)(u + (rowbase + m) * DD + 32 + quad * 8);

    f32x4 acc[4];
#pragma unroll
    for (int c = 0; c < 4; ++c) {
        f32x4 z = {0.f, 0.f, 0.f, 0.f};
        z = __builtin_amdgcn_mfma_f32_16x16x32_f16(a0, bf[c][0], z, 0, 0, 0);
        z = __builtin_amdgcn_mfma_f32_16x16x32_f16(a1, bf[c][1], z, 0, 0, 0);
        acc[c] = z;
    }

#pragma unroll
    for (int c = 0; c < 4; ++c) {
        const float bv = bias[c * 16 + m];
#pragma unroll
        for (int r = 0; r < 4; ++r) {
            const size_t row = rowbase + quad * 4 + r;
            const float val = acc[c][r] + bv;
            if (HALF_OUT) ((_Float16*)outp)[row * DD + c * 16 + m] = (_Float16)val;
            else          ((float*)    outp)[row * DD + c * 16 + m] = val;
        }
    }
}

extern "C" void kernel_launch(void* const* d_in, const int* in_sizes, int n_in,
                              void* d_out, int out_size, void* d_ws, size_t ws_size,
                              hipStream_t stream) {
    const int*   edge_index  = (const int*)  d_in[0];
    const float* edge_weight = (const float*)d_in[1];
    const float* user_emb    = (const float*)d_in[2];
    const float* item_emb    = (const float*)d_in[3];
    const float* W1          = (const float*)d_in[4];
    const float* b1          = (const float*)d_in[5];
    const float* W2          = (const float*)d_in[6];
    const float* b2          = (const float*)d_in[7];
    float*       out         = (float*)d_out;

    // Workspace layout:
    char* ws = (char*)d_ws;
    _Float16* xh      = (_Float16*)(ws);                 // 25,600,000 B — xh, then h1 aliases it
    _Float16* u       = (_Float16*)(ws + 25600000);      // 25,600,000 B
    int2*     edges   = (int2*)    (ws + 51200000);      // 25,600,000 B
    int*      row_ptr = (int*)     (ws + 76800000);      //    800,064 B
    int*      ofs     = (int*)     (ws + 77600064);      //    800,000 B
    int*      counts  = (int*)     (ws + 78400064);      //    800,000 B
    int*      bsum    = (int*)     (ws + 79200064);      //        512 B
    _Float16* Wt      = (_Float16*)(ws + 79200576);      //     16,384 B

    const int edge_blocks = (EE + 255) / 256;            // 12500
    const int node_blocks = NN / 4;                      // 50000
    const int gemm_blocks = (NN / 16) / 4;               // 3125

    // ---- CSR build ----
    hipMemsetAsync(counts, 0, NN * sizeof(int), stream);
    hist_kernel         <<<edge_blocks, 256, 0, stream>>>(edge_index, counts);
    scan_partials_kernel<<<NB_SCAN,     256, 0, stream>>>(counts, bsum);
    scan_top_kernel     <<<1,           128, 0, stream>>>(bsum);
    scan_write_kernel   <<<NB_SCAN,     256, 0, stream>>>(counts, bsum, row_ptr, ofs);
    reorder_kernel      <<<edge_blocks, 256, 0, stream>>>(edge_index, edge_weight,
                                                          ofs, edges);

    // ---- fp16 conversions ----
    convert_x_kernel<<<(NN * DD / 4 + 255) / 256, 256, 0, stream>>>(user_emb, item_emb, xh);
    convert_w_kernel<<<(2 * DD * DD + 255) / 256, 256, 0, stream>>>(W1, W2, Wt);

    // ---- Layer 1 ----
    aggregate_kernel<<<node_blocks, 256, 0, stream>>>(edges, row_ptr, xh, u);
    gemm64_kernel<true><<<gemm_blocks, 256, 0, stream>>>(u, Wt, b1, (void*)xh);

    // ---- Layer 2 ----
    aggregate_kernel<<<node_blocks, 256, 0, stream>>>(edges, row_ptr, xh, u);
    gemm64_kernel<false><<<gemm_blocks, 256, 0, stream>>>(u, Wt + DD * DD, b2, (void*)out);
}

// Round 5
// 667.352 us; speedup vs baseline: 1.2628x; 1.2628x over previous
//
#include <hip/hip_runtime.h>
#include <hip/hip_fp16.h>

#define NUM_USERS 100000
#define NN        200000          // N = users + items
#define DD        64
#define EE        3200000
#define SCAN_CHUNK 2048
#define NB_SCAN   98              // covers up to 200704 elements

#define KB_   391                 // dst buckets: 512 nodes each (dst >> 9)
#define GSEG  512                 // edge segments
#define EPS   (EE / GSEG)         // 6250 edges per segment
#define MSEG  (KB_ * GSEG)        // 200192 (bucket,segment) counters

typedef _Float16 half8 __attribute__((ext_vector_type(8)));
typedef _Float16 half4 __attribute__((ext_vector_type(4)));
typedef float    f32x4 __attribute__((ext_vector_type(4)));

// ---------------------------------------------------------------------------
// Node-degree histogram (for row_ptr)
// ---------------------------------------------------------------------------
__global__ __launch_bounds__(256) void hist_kernel(
    const int* __restrict__ ei, int* __restrict__ counts)
{
    const int e = blockIdx.x * 256 + threadIdx.x;
    if (e < EE) atomicAdd(&counts[ei[EE + e]], 1);
}

// ---------------------------------------------------------------------------
// Generic 3-phase exclusive scan (len <= NB_SCAN*SCAN_CHUNK)
// ---------------------------------------------------------------------------
__global__ __launch_bounds__(256) void scan_partials_kernel(
    const int* __restrict__ counts, int* __restrict__ bsum, int len)
{
    __shared__ int s[256];
    const int t = threadIdx.x;
    int sum = 0;
    for (int i = t; i < SCAN_CHUNK; i += 256) {
        const int idx = blockIdx.x * SCAN_CHUNK + i;
        sum += (idx < len) ? counts[idx] : 0;
    }
    s[t] = sum; __syncthreads();
    for (int off = 128; off > 0; off >>= 1) {
        if (t < off) s[t] += s[t + off];
        __syncthreads();
    }
    if (t == 0) bsum[blockIdx.x] = s[0];
}

__global__ __launch_bounds__(128) void scan_top_kernel(int* __restrict__ bsum, int nb)
{
    __shared__ int s[128];
    const int t = threadIdx.x;
    const int v = (t < nb) ? bsum[t] : 0;
    s[t] = v; __syncthreads();
    for (int off = 1; off < 128; off <<= 1) {
        int add = (t >= off) ? s[t - off] : 0;
        __syncthreads();
        s[t] += add;
        __syncthreads();
    }
    if (t < nb) bsum[t] = s[t] - v;   // exclusive
}

__global__ __launch_bounds__(256) void scan_write_kernel(
    const int* __restrict__ counts, const int* __restrict__ bsum,
    int* __restrict__ out, int len, int sentinel)
{
    __shared__ int s[256];
    const int t    = threadIdx.x;
    const int base = blockIdx.x * SCAN_CHUNK + t * 8;
    int c[8], ex[8], run = 0;
#pragma unroll
    for (int j = 0; j < 8; ++j) {
        const int idx = base + j;
        c[j] = (idx < len) ? counts[idx] : 0;
        ex[j] = run; run += c[j];
    }
    s[t] = run; __syncthreads();
    for (int off = 1; off < 256; off <<= 1) {
        int add = (t >= off) ? s[t - off] : 0;
        __syncthreads();
        s[t] += add;
        __syncthreads();
    }
    const int thread_base = bsum[blockIdx.x] + s[t] - run;
#pragma unroll
    for (int j = 0; j < 8; ++j) {
        const int idx = base + j;
        if (idx < len) out[idx] = thread_base + ex[j];
    }
    if (sentinel >= 0 && blockIdx.x == 0 && t == 0) out[len] = sentinel;
}

// ---------------------------------------------------------------------------
// Pass A1: per-(bucket,segment) histogram. Workgroup s owns edges
// [s*EPS,(s+1)*EPS); LDS histogram over 391 buckets; non-atomic global write.
// ---------------------------------------------------------------------------
__global__ __launch_bounds__(256) void seg_hist_kernel(
    const int* __restrict__ ei, int* __restrict__ counts_seg)
{
    __shared__ int h[KB_];
    const int s = blockIdx.x;
    for (int k = threadIdx.x; k < KB_; k += 256) h[k] = 0;
    __syncthreads();
    const int base = s * EPS;
    for (int i = threadIdx.x; i < EPS; i += 256) {
        const int dst = __builtin_nontemporal_load(&ei[EE + base + i]);
        atomicAdd(&h[dst >> 9], 1);
    }
    __syncthreads();
    for (int k = threadIdx.x; k < KB_; k += 256)
        counts_seg[k * GSEG + s] = h[k];
}

// ---------------------------------------------------------------------------
// Pass A2: append edges into bucket-grouped order. Each workgroup owns its
// (k,s) output runs exclusively -> lines filled by one workgroup/XCD ->
// writeback ~ edge bytes (the locality fix for round 3/4's 200 MB WRITE_SIZE).
// Record: x = src | dst_local<<18 (src<2^18, dst_local<2^9), y = w bits.
// ---------------------------------------------------------------------------
__global__ __launch_bounds__(256) void append_kernel(
    const int* __restrict__ ei, const float* __restrict__ ew,
    const int* __restrict__ bofs, int2* __restrict__ etmp)
{
    __shared__ int fr[KB_];
    const int s = blockIdx.x;
    for (int k = threadIdx.x; k < KB_; k += 256) fr[k] = bofs[k * GSEG + s];
    __syncthreads();
    const int base = s * EPS;
    for (int i = threadIdx.x; i < EPS; i += 256) {
        const int e   = base + i;
        const int   src = __builtin_nontemporal_load(&ei[e]);
        const int   dst = __builtin_nontemporal_load(&ei[EE + e]);
        const float w   = __builtin_nontemporal_load(&ew[e]);
        const int k  = dst >> 9;
        const int dl = dst & 511;
        const int pos = atomicAdd(&fr[k], 1);   // LDS atomic
        etmp[pos] = make_int2(src | (dl << 18), __float_as_int(w));
    }
}

// ---------------------------------------------------------------------------
// Pass B: exact dst-sort within each bucket. Scatter confined to the bucket's
// ~64 KB output window -> L2-resident, lines coalesce before eviction.
// ---------------------------------------------------------------------------
__global__ __launch_bounds__(256) void bucket_sort_kernel(
    const int2* __restrict__ etmp, const int* __restrict__ bofs,
    const int* __restrict__ row_ptr, int2* __restrict__ edges)
{
    __shared__ int cnt[512];
    const int k = blockIdx.x;
    for (int j = threadIdx.x; j < 512; j += 256) {
        const int node = (k << 9) + j;
        cnt[j] = (node < NN) ? row_ptr[node] : 0;
    }
    __syncthreads();
    const int beg = bofs[k * GSEG];
    const int end = (k == KB_ - 1) ? EE : bofs[(k + 1) * GSEG];
    for (int e = beg + threadIdx.x; e < end; e += 256) {
        const int2 r  = etmp[e];
        const int  dl  = ((unsigned)r.x) >> 18;
        const int  src = r.x & 0x3FFFF;
        const int  pos = atomicAdd(&cnt[dl], 1);   // LDS atomic
        edges[pos] = make_int2(src, r.y);
    }
}

// ---------------------------------------------------------------------------
// fp32 embeddings -> fp16 gather table xh [N][64]
// ---------------------------------------------------------------------------
__global__ __launch_bounds__(256) void convert_x_kernel(
    const float* __restrict__ xu, const float* __restrict__ xi,
    _Float16* __restrict__ xh)
{
    const int i = blockIdx.x * 256 + threadIdx.x;
    if (i >= NN * DD / 4) return;
    const float4 v = (i < NUM_USERS * DD / 4)
                       ? ((const float4*)xu)[i]
                       : ((const float4*)xi)[i - NUM_USERS * DD / 4];
    half4 o; o[0] = (_Float16)v.x; o[1] = (_Float16)v.y;
             o[2] = (_Float16)v.z; o[3] = (_Float16)v.w;
    ((half4*)xh)[i] = o;
}

// W [k][n] fp32 -> Wt [n][k] fp16
__global__ __launch_bounds__(256) void convert_w_kernel(
    const float* __restrict__ W1, const float* __restrict__ W2,
    _Float16* __restrict__ Wt)
{
    const int idx = blockIdx.x * 256 + threadIdx.x;
    if (idx >= 2 * DD * DD) return;
    const int mat = idx >> 12, rem = idx & 4095, k = rem >> 6, n = rem & 63;
    const float* W = mat ? W2 : W1;
    Wt[mat * DD * DD + n * DD + k] = (_Float16)W[k * DD + n];
}

// ---------------------------------------------------------------------------
// Aggregation: one wave per node, lane d = dim d (unchanged from round 3).
// ---------------------------------------------------------------------------
__global__ __launch_bounds__(256) void aggregate_kernel(
    const int2* __restrict__ edges, const int* __restrict__ row_ptr,
    const _Float16* __restrict__ xh, _Float16* __restrict__ u)
{
    const int node = blockIdx.x * 4 + (threadIdx.x >> 6);
    const int lane = threadIdx.x & 63;

    float acc = (float)xh[(size_t)node * DD + lane];
    const int beg = row_ptr[node];
    const int end = row_ptr[node + 1];
    int e = beg;
    for (; e + 4 <= end; e += 4) {
        const int2 p0 = edges[e + 0];
        const int2 p1 = edges[e + 1];
        const int2 p2 = edges[e + 2];
        const int2 p3 = edges[e + 3];
        const float v0 = (float)xh[(size_t)p0.x * DD + lane];
        const float v1 = (float)xh[(size_t)p1.x * DD + lane];
        const float v2 = (float)xh[(size_t)p2.x * DD + lane];
        const float v3 = (float)xh[(size_t)p3.x * DD + lane];
        acc = fmaf(__int_as_float(p0.y), v0, acc);
        acc = fmaf(__int_as_float(p1.y), v1, acc);
        acc = fmaf(__int_as_float(p2.y), v2, acc);
        acc = fmaf(__int_as_float(p3.y), v3, acc);
    }
    for (; e < end; ++e) {
        const int2 p = edges[e];
        acc = fmaf(__int_as_float(p.y), (float)xh[(size_t)p.x * DD + lane], acc);
    }
    u[(size_t)node * DD + lane] = (_Float16)(acc * 0.5f);
}

// ---------------------------------------------------------------------------
// GEMM: out[N,64] = u[N,64] @ W[64,64] + b (unchanged from round 3)
// ---------------------------------------------------------------------------
template<bool HALF_OUT>
__global__ __launch_bounds__(256) void gemm64_kernel(
    const _Float16* __restrict__ u, const _Float16* __restrict__ Wt,
    const float* __restrict__ bias, void* __restrict__ outp)
{
    const int wid  = blockIdx.x * 4 + (threadIdx.x >> 6);
    const int lane = threadIdx.x & 63;
    const int m    = lane & 15;
    const int quad = lane >> 4;
    const size_t rowbase = (size_t)wid * 16;

    half8 bf[4][2];
#pragma unroll
    for (int c = 0; c < 4; ++c)
#pragma unroll
        for (int h = 0; h < 2; ++h)
            bf[c][h] = *(const half8*)(Wt + (size_t)(c * 16 + m) * DD + h * 32 + quad * 8);

    const half8 a0 = *(const half8*)(u + (rowbase + m) * DD +  0 + quad * 8);
    const half8 a1 = *(const half8*)(u + (rowbase + m) * DD + 32 + quad * 8);

    f32x4 acc[4];
#pragma unroll
    for (int c = 0; c < 4; ++c) {
        f32x4 z = {0.f, 0.f, 0.f, 0.f};
        z = __builtin_amdgcn_mfma_f32_16x16x32_f16(a0, bf[c][0], z, 0, 0, 0);
        z = __builtin_amdgcn_mfma_f32_16x16x32_f16(a1, bf[c][1], z, 0, 0, 0);
        acc[c] = z;
    }

#pragma unroll
    for (int c = 0; c < 4; ++c) {
        const float bv = bias[c * 16 + m];
#pragma unroll
        for (int r = 0; r < 4; ++r) {
            const size_t row = rowbase + quad * 4 + r;
            const float val = acc[c][r] + bv;
            if (HALF_OUT) ((_Float16*)outp)[row * DD + c * 16 + m] = (_Float16)val;
            else          ((float*)    outp)[row * DD + c * 16 + m] = val;
        }
    }
}

extern "C" void kernel_launch(void* const* d_in, const int* in_sizes, int n_in,
                              void* d_out, int out_size, void* d_ws, size_t ws_size,
                              hipStream_t stream) {
    const int*   edge_index  = (const int*)  d_in[0];
    const float* edge_weight = (const float*)d_in[1];
    const float* user_emb    = (const float*)d_in[2];
    const float* item_emb    = (const float*)d_in[3];
    const float* W1          = (const float*)d_in[4];
    const float* b1          = (const float*)d_in[5];
    const float* W2          = (const float*)d_in[6];
    const float* b2          = (const float*)d_in[7];
    float*       out         = (float*)d_out;

    // Workspace layout:
    char* ws = (char*)d_ws;
    _Float16* xh        = (_Float16*)(ws);               // 25,600,000 B (h1 aliases after layer 1)
    _Float16* u         = (_Float16*)(ws + 25600000);    // 25,600,000 B — also etmp during build
    int2*     etmp      = (int2*)    (ws + 25600000);    //   (alias of u)
    int2*     edges     = (int2*)    (ws + 51200000);    // 25,600,000 B (dst-sorted)
    int*      row_ptr   = (int*)     (ws + 76800000);    //    800,064 B
    int*      counts    = (int*)     (ws + 77600064);    //    800,000 B (node degrees)
    int*      cseg      = (int*)     (ws + 78400064);    //    800,768 B (MSEG counters)
    int*      bofs      = (int*)     (ws + 79200832);    //    800,768 B (scanned MSEG)
    int*      bsum      = (int*)     (ws + 80001600);    //        512 B
    _Float16* Wt        = (_Float16*)(ws + 80002112);    //     16,384 B

    const int edge_blocks = (EE + 255) / 256;            // 12500
    const int node_blocks = NN / 4;                      // 50000
    const int gemm_blocks = (NN / 16) / 4;               // 3125

    // ---- row_ptr (node-level scan) ----
    hipMemsetAsync(counts, 0, NN * sizeof(int), stream);
    hist_kernel        <<<edge_blocks, 256, 0, stream>>>(edge_index, counts);
    scan_partials_kernel<<<NB_SCAN,    256, 0, stream>>>(counts, bsum, NN);
    scan_top_kernel     <<<1,          128, 0, stream>>>(bsum, NB_SCAN);
    scan_write_kernel   <<<NB_SCAN,    256, 0, stream>>>(counts, bsum, row_ptr, NN, EE);

    // ---- bucket partition (segment-level scan) ----
    seg_hist_kernel     <<<GSEG,       256, 0, stream>>>(edge_index, cseg);
    scan_partials_kernel<<<NB_SCAN,    256, 0, stream>>>(cseg, bsum, MSEG);
    scan_top_kernel     <<<1,          128, 0, stream>>>(bsum, NB_SCAN);
    scan_write_kernel   <<<NB_SCAN,    256, 0, stream>>>(cseg, bsum, bofs, MSEG, -1);

    // ---- append into buckets, then exact sort within buckets ----
    append_kernel      <<<GSEG, 256, 0, stream>>>(edge_index, edge_weight, bofs, etmp);
    bucket_sort_kernel <<<KB_,  256, 0, stream>>>(etmp, bofs, row_ptr, edges);

    // ---- fp16 conversions ----
    convert_x_kernel<<<(NN * DD / 4 + 255) / 256, 256, 0, stream>>>(user_emb, item_emb, xh);
    convert_w_kernel<<<(2 * DD * DD + 255) / 256, 256, 0, stream>>>(W1, W2, Wt);

    // ---- Layer 1 ----
    aggregate_kernel<<<node_blocks, 256, 0, stream>>>(edges, row_ptr, xh, u);
    gemm64_kernel<true><<<gemm_blocks, 256, 0, stream>>>(u, Wt, b1, (void*)xh);

    // ---- Layer 2 ----
    aggregate_kernel<<<node_blocks, 256, 0, stream>>>(edges, row_ptr, xh, u);
    gemm64_kernel<false><<<gemm_blocks, 256, 0, stream>>>(u, Wt + DD * DD, b2, (void*)out);
}

// Round 6
// 491.892 us; speedup vs baseline: 1.7132x; 1.3567x over previous
//
#include <hip/hip_runtime.h>
#include <hip/hip_fp16.h>

#define NUM_USERS 100000
#define NN        200000          // N = users + items
#define DD        64
#define EE        3200000
#define SCAN_CHUNK 2048
#define NB_SCAN   98              // covers up to 200704 elements

#define KB_   391                 // dst buckets: 512 nodes each (dst >> 9)
#define GSEG  512                 // edge segments
#define EPS   (EE / GSEG)         // 6250 edges per segment
#define MSEG  (KB_ * GSEG)        // 200192 (bucket,segment) counters

typedef _Float16 half8 __attribute__((ext_vector_type(8)));
typedef _Float16 half4 __attribute__((ext_vector_type(4)));
typedef float    f32x4 __attribute__((ext_vector_type(4)));

// ---------------------------------------------------------------------------
// Generic 3-phase exclusive scan (len <= NB_SCAN*SCAN_CHUNK) — used only for
// the (bucket,segment) counter array now.
// ---------------------------------------------------------------------------
__global__ __launch_bounds__(256) void scan_partials_kernel(
    const int* __restrict__ counts, int* __restrict__ bsum, int len)
{
    __shared__ int s[256];
    const int t = threadIdx.x;
    int sum = 0;
    for (int i = t; i < SCAN_CHUNK; i += 256) {
        const int idx = blockIdx.x * SCAN_CHUNK + i;
        sum += (idx < len) ? counts[idx] : 0;
    }
    s[t] = sum; __syncthreads();
    for (int off = 128; off > 0; off >>= 1) {
        if (t < off) s[t] += s[t + off];
        __syncthreads();
    }
    if (t == 0) bsum[blockIdx.x] = s[0];
}

__global__ __launch_bounds__(128) void scan_top_kernel(int* __restrict__ bsum, int nb)
{
    __shared__ int s[128];
    const int t = threadIdx.x;
    const int v = (t < nb) ? bsum[t] : 0;
    s[t] = v; __syncthreads();
    for (int off = 1; off < 128; off <<= 1) {
        int add = (t >= off) ? s[t - off] : 0;
        __syncthreads();
        s[t] += add;
        __syncthreads();
    }
    if (t < nb) bsum[t] = s[t] - v;   // exclusive
}

__global__ __launch_bounds__(256) void scan_write_kernel(
    const int* __restrict__ counts, const int* __restrict__ bsum,
    int* __restrict__ out, int len)
{
    __shared__ int s[256];
    const int t    = threadIdx.x;
    const int base = blockIdx.x * SCAN_CHUNK + t * 8;
    int c[8], ex[8], run = 0;
#pragma unroll
    for (int j = 0; j < 8; ++j) {
        const int idx = base + j;
        c[j] = (idx < len) ? counts[idx] : 0;
        ex[j] = run; run += c[j];
    }
    s[t] = run; __syncthreads();
    for (int off = 1; off < 256; off <<= 1) {
        int add = (t >= off) ? s[t - off] : 0;
        __syncthreads();
        s[t] += add;
        __syncthreads();
    }
    const int thread_base = bsum[blockIdx.x] + s[t] - run;
#pragma unroll
    for (int j = 0; j < 8; ++j) {
        const int idx = base + j;
        if (idx < len) out[idx] = thread_base + ex[j];
    }
}

// ---------------------------------------------------------------------------
// Pass A1: per-(bucket,segment) histogram.
// ---------------------------------------------------------------------------
__global__ __launch_bounds__(256) void seg_hist_kernel(
    const int* __restrict__ ei, int* __restrict__ counts_seg)
{
    __shared__ int h[KB_];
    const int s = blockIdx.x;
    for (int k = threadIdx.x; k < KB_; k += 256) h[k] = 0;
    __syncthreads();
    const int base = s * EPS;
    for (int i = threadIdx.x; i < EPS; i += 256) {
        const int dst = __builtin_nontemporal_load(&ei[EE + base + i]);
        atomicAdd(&h[dst >> 9], 1);
    }
    __syncthreads();
    for (int k = threadIdx.x; k < KB_; k += 256)
        counts_seg[k * GSEG + s] = h[k];
}

// ---------------------------------------------------------------------------
// Pass A2: append edges into bucket-grouped order (locality-preserving).
// Record: x = src | dst_local<<18, y = w bits.
// ---------------------------------------------------------------------------
__global__ __launch_bounds__(256) void append_kernel(
    const int* __restrict__ ei, const float* __restrict__ ew,
    const int* __restrict__ bofs, int2* __restrict__ etmp)
{
    __shared__ int fr[KB_];
    const int s = blockIdx.x;
    for (int k = threadIdx.x; k < KB_; k += 256) fr[k] = bofs[k * GSEG + s];
    __syncthreads();
    const int base = s * EPS;
    for (int i = threadIdx.x; i < EPS; i += 256) {
        const int e   = base + i;
        const int   src = __builtin_nontemporal_load(&ei[e]);
        const int   dst = __builtin_nontemporal_load(&ei[EE + e]);
        const float w   = __builtin_nontemporal_load(&ew[e]);
        const int k  = dst >> 9;
        const int dl = dst & 511;
        const int pos = atomicAdd(&fr[k], 1);   // LDS atomic
        etmp[pos] = make_int2(src | (dl << 18), __float_as_int(w));
    }
}

// ---------------------------------------------------------------------------
// Pass B: exact dst-sort within each bucket + row_ptr construction (NEW:
// folds the old hist + node-scan kernels). Bucket k reads its etmp range
// twice: count into LDS -> LDS exclusive scan (gives row_ptr for the
// bucket's 512 nodes, written non-atomically) -> scatter into final order.
// Output record: x = src*128 (byte offset into fp16 table), y = w bits.
// ---------------------------------------------------------------------------
__global__ __launch_bounds__(256) void bucket_sort_kernel(
    const int2* __restrict__ etmp, const int* __restrict__ bofs,
    int2* __restrict__ edges, int* __restrict__ row_ptr)
{
    __shared__ int cnt[512];
    __shared__ int cur[512];
    __shared__ int part[256];
    const int k = blockIdx.x;
    const int t = threadIdx.x;
    cnt[t] = 0; cnt[t + 256] = 0;
    __syncthreads();
    const int beg = bofs[k * GSEG];
    const int end = (k == KB_ - 1) ? EE : bofs[(k + 1) * GSEG];
    for (int e = beg + t; e < end; e += 256)
        atomicAdd(&cnt[((unsigned)etmp[e].x) >> 18], 1);
    __syncthreads();
    const int c0 = cnt[2 * t], c1 = cnt[2 * t + 1];
    const int run = c0 + c1;
    part[t] = run; __syncthreads();
    for (int off = 1; off < 256; off <<= 1) {
        int add = (t >= off) ? part[t - off] : 0;
        __syncthreads();
        part[t] += add;
        __syncthreads();
    }
    const int base = beg + part[t] - run;         // exclusive prefix + bucket base
    cur[2 * t]     = base;
    cur[2 * t + 1] = base + c0;
    const int node0 = (k << 9) + 2 * t;
    if (node0 < NN)     row_ptr[node0]     = base;
    if (node0 + 1 < NN) row_ptr[node0 + 1] = base + c0;
    if (k == KB_ - 1 && t == 0) row_ptr[NN] = EE;
    __syncthreads();
    for (int e = beg + t; e < end; e += 256) {
        const int2 r  = etmp[e];
        const int  dl = ((unsigned)r.x) >> 18;
        const int  pos = atomicAdd(&cur[dl], 1);  // LDS atomic
        edges[pos] = make_int2((r.x & 0x3FFFF) << 7, r.y);   // src byte-offset
    }
}

// ---------------------------------------------------------------------------
// fp32 embeddings -> fp16 gather table xh [N][64]
// ---------------------------------------------------------------------------
__global__ __launch_bounds__(256) void convert_x_kernel(
    const float* __restrict__ xu, const float* __restrict__ xi,
    _Float16* __restrict__ xh)
{
    const int i = blockIdx.x * 256 + threadIdx.x;
    if (i >= NN * DD / 4) return;
    const float4 v = (i < NUM_USERS * DD / 4)
                       ? ((const float4*)xu)[i]
                       : ((const float4*)xi)[i - NUM_USERS * DD / 4];
    half4 o; o[0] = (_Float16)v.x; o[1] = (_Float16)v.y;
             o[2] = (_Float16)v.z; o[3] = (_Float16)v.w;
    ((half4*)xh)[i] = o;
}

// W [k][n] fp32 -> Wt [n][k] fp16
__global__ __launch_bounds__(256) void convert_w_kernel(
    const float* __restrict__ W1, const float* __restrict__ W2,
    _Float16* __restrict__ Wt)
{
    const int idx = blockIdx.x * 256 + threadIdx.x;
    if (idx >= 2 * DD * DD) return;
    const int mat = idx >> 12, rem = idx & 4095, k = rem >> 6, n = rem & 63;
    const float* W = mat ? W2 : W1;
    Wt[mat * DD * DD + n * DD + k] = (_Float16)W[k * DD + n];
}

// ---------------------------------------------------------------------------
// Aggregation: one wave per TWO adjacent node rows, lane d = dim d.
// Dual unroll-4 interleave -> 8 independent gathers in flight; edge records
// carry pre-scaled byte offsets so per-gather addressing is one v_add.
// ---------------------------------------------------------------------------
__global__ __launch_bounds__(256) void aggregate_kernel(
    const int2* __restrict__ edges, const int* __restrict__ row_ptr,
    const _Float16* __restrict__ xh, _Float16* __restrict__ u)
{
    const int wave = (blockIdx.x * 256 + threadIdx.x) >> 6;  // 0..99999
    const int lane = threadIdx.x & 63;
    const unsigned lane2 = lane * 2;
    const int n0 = wave * 2;
    const int n1 = n0 + 1;
    const char* xb = (const char*)xh;

    float acc0 = (float)*(const _Float16*)(xb + ((unsigned)n0 << 7) + lane2);
    float acc1 = (float)*(const _Float16*)(xb + ((unsigned)n1 << 7) + lane2);

    int       e0   = row_ptr[n0];
    const int end0 = row_ptr[n1];        // rows adjacent: end0 == beg1
    int       e1   = end0;
    const int end1 = row_ptr[n1 + 1];

    // steady state: 8 gathers from 2 independent streams in flight
    while (e0 + 4 <= end0 && e1 + 4 <= end1) {
        const int2 a0 = edges[e0 + 0], a1 = edges[e0 + 1];
        const int2 a2 = edges[e0 + 2], a3 = edges[e0 + 3];
        const int2 b0 = edges[e1 + 0], b1 = edges[e1 + 1];
        const int2 b2 = edges[e1 + 2], b3 = edges[e1 + 3];
        const float va0 = (float)*(const _Float16*)(xb + (unsigned)a0.x + lane2);
        const float va1 = (float)*(const _Float16*)(xb + (unsigned)a1.x + lane2);
        const float va2 = (float)*(const _Float16*)(xb + (unsigned)a2.x + lane2);
        const float va3 = (float)*(const _Float16*)(xb + (unsigned)a3.x + lane2);
        const float vb0 = (float)*(const _Float16*)(xb + (unsigned)b0.x + lane2);
        const float vb1 = (float)*(const _Float16*)(xb + (unsigned)b1.x + lane2);
        const float vb2 = (float)*(const _Float16*)(xb + (unsigned)b2.x + lane2);
        const float vb3 = (float)*(const _Float16*)(xb + (unsigned)b3.x + lane2);
        acc0 = fmaf(__int_as_float(a0.y), va0, acc0);
        acc0 = fmaf(__int_as_float(a1.y), va1, acc0);
        acc0 = fmaf(__int_as_float(a2.y), va2, acc0);
        acc0 = fmaf(__int_as_float(a3.y), va3, acc0);
        acc1 = fmaf(__int_as_float(b0.y), vb0, acc1);
        acc1 = fmaf(__int_as_float(b1.y), vb1, acc1);
        acc1 = fmaf(__int_as_float(b2.y), vb2, acc1);
        acc1 = fmaf(__int_as_float(b3.y), vb3, acc1);
        e0 += 4; e1 += 4;
    }
    // drain stream 0
    for (; e0 + 4 <= end0; e0 += 4) {
        const int2 a0 = edges[e0 + 0], a1 = edges[e0 + 1];
        const int2 a2 = edges[e0 + 2], a3 = edges[e0 + 3];
        const float va0 = (float)*(const _Float16*)(xb + (unsigned)a0.x + lane2);
        const float va1 = (float)*(const _Float16*)(xb + (unsigned)a1.x + lane2);
        const float va2 = (float)*(const _Float16*)(xb + (unsigned)a2.x + lane2);
        const float va3 = (float)*(const _Float16*)(xb + (unsigned)a3.x + lane2);
        acc0 = fmaf(__int_as_float(a0.y), va0, acc0);
        acc0 = fmaf(__int_as_float(a1.y), va1, acc0);
        acc0 = fmaf(__int_as_float(a2.y), va2, acc0);
        acc0 = fmaf(__int_as_float(a3.y), va3, acc0);
    }
    for (; e0 < end0; ++e0) {
        const int2 p = edges[e0];
        acc0 = fmaf(__int_as_float(p.y),
                    (float)*(const _Float16*)(xb + (unsigned)p.x + lane2), acc0);
    }
    // drain stream 1
    for (; e1 + 4 <= end1; e1 += 4) {
        const int2 b0 = edges[e1 + 0], b1 = edges[e1 + 1];
        const int2 b2 = edges[e1 + 2], b3 = edges[e1 + 3];
        const float vb0 = (float)*(const _Float16*)(xb + (unsigned)b0.x + lane2);
        const float vb1 = (float)*(const _Float16*)(xb + (unsigned)b1.x + lane2);
        const float vb2 = (float)*(const _Float16*)(xb + (unsigned)b2.x + lane2);
        const float vb3 = (float)*(const _Float16*)(xb + (unsigned)b3.x + lane2);
        acc1 = fmaf(__int_as_float(b0.y), vb0, acc1);
        acc1 = fmaf(__int_as_float(b1.y), vb1, acc1);
        acc1 = fmaf(__int_as_float(b2.y), vb2, acc1);
        acc1 = fmaf(__int_as_float(b3.y), vb3, acc1);
    }
    for (; e1 < end1; ++e1) {
        const int2 p = edges[e1];
        acc1 = fmaf(__int_as_float(p.y),
                    (float)*(const _Float16*)(xb + (unsigned)p.x + lane2), acc1);
    }

    char* ub = (char*)u;
    *(_Float16*)(ub + ((unsigned)n0 << 7) + lane2) = (_Float16)(acc0 * 0.5f);
    *(_Float16*)(ub + ((unsigned)n1 << 7) + lane2) = (_Float16)(acc1 * 0.5f);
}

// ---------------------------------------------------------------------------
// GEMM: out[N,64] = u[N,64] @ W[64,64] + b (unchanged)
// ---------------------------------------------------------------------------
template<bool HALF_OUT>
__global__ __launch_bounds__(256) void gemm64_kernel(
    const _Float16* __restrict__ u, const _Float16* __restrict__ Wt,
    const float* __restrict__ bias, void* __restrict__ outp)
{
    const int wid  = blockIdx.x * 4 + (threadIdx.x >> 6);
    const int lane = threadIdx.x & 63;
    const int m    = lane & 15;
    const int quad = lane >> 4;
    const size_t rowbase = (size_t)wid * 16;

    half8 bf[4][2];
#pragma unroll
    for (int c = 0; c < 4; ++c)
#pragma unroll
        for (int h = 0; h < 2; ++h)
            bf[c][h] = *(const half8*)(Wt + (size_t)(c * 16 + m) * DD + h * 32 + quad * 8);

    const half8 a0 = *(const half8*)(u + (rowbase + m) * DD +  0 + quad * 8);
    const half8 a1 = *(const half8*)(u + (rowbase + m) * DD + 32 + quad * 8);

    f32x4 acc[4];
#pragma unroll
    for (int c = 0; c < 4; ++c) {
        f32x4 z = {0.f, 0.f, 0.f, 0.f};
        z = __builtin_amdgcn_mfma_f32_16x16x32_f16(a0, bf[c][0], z, 0, 0, 0);
        z = __builtin_amdgcn_mfma_f32_16x16x32_f16(a1, bf[c][1], z, 0, 0, 0);
        acc[c] = z;
    }

#pragma unroll
    for (int c = 0; c < 4; ++c) {
        const float bv = bias[c * 16 + m];
#pragma unroll
        for (int r = 0; r < 4; ++r) {
            const size_t row = rowbase + quad * 4 + r;
            const float val = acc[c][r] + bv;
            if (HALF_OUT) ((_Float16*)outp)[row * DD + c * 16 + m] = (_Float16)val;
            else          ((float*)    outp)[row * DD + c * 16 + m] = val;
        }
    }
}

extern "C" void kernel_launch(void* const* d_in, const int* in_sizes, int n_in,
                              void* d_out, int out_size, void* d_ws, size_t ws_size,
                              hipStream_t stream) {
    const int*   edge_index  = (const int*)  d_in[0];
    const float* edge_weight = (const float*)d_in[1];
    const float* user_emb    = (const float*)d_in[2];
    const float* item_emb    = (const float*)d_in[3];
    const float* W1          = (const float*)d_in[4];
    const float* b1          = (const float*)d_in[5];
    const float* W2          = (const float*)d_in[6];
    const float* b2          = (const float*)d_in[7];
    float*       out         = (float*)d_out;

    // Workspace layout:
    char* ws = (char*)d_ws;
    _Float16* xh        = (_Float16*)(ws);               // 25,600,000 B (h1 aliases after layer 1)
    _Float16* u         = (_Float16*)(ws + 25600000);    // 25,600,000 B — also etmp during build
    int2*     etmp      = (int2*)    (ws + 25600000);    //   (alias of u)
    int2*     edges     = (int2*)    (ws + 51200000);    // 25,600,000 B (dst-sorted)
    int*      row_ptr   = (int*)     (ws + 76800000);    //    800,064 B
    int*      cseg      = (int*)     (ws + 78400064);    //    800,768 B (MSEG counters)
    int*      bofs      = (int*)     (ws + 79200832);    //    800,768 B (scanned MSEG)
    int*      bsum      = (int*)     (ws + 80001600);    //        512 B
    _Float16* Wt        = (_Float16*)(ws + 80002112);    //     16,384 B

    const int gemm_blocks = (NN / 16) / 4;               // 3125
    const int agg_blocks  = NN / 8;                      // 25000 (2 nodes/wave, 4 waves/block)

    // ---- bucket partition (segment-level scan) ----
    seg_hist_kernel     <<<GSEG,    256, 0, stream>>>(edge_index, cseg);
    scan_partials_kernel<<<NB_SCAN, 256, 0, stream>>>(cseg, bsum, MSEG);
    scan_top_kernel     <<<1,       128, 0, stream>>>(bsum, NB_SCAN);
    scan_write_kernel   <<<NB_SCAN, 256, 0, stream>>>(cseg, bsum, bofs, MSEG);

    // ---- append into buckets, then exact sort (also builds row_ptr) ----
    append_kernel      <<<GSEG, 256, 0, stream>>>(edge_index, edge_weight, bofs, etmp);
    bucket_sort_kernel <<<KB_,  256, 0, stream>>>(etmp, bofs, edges, row_ptr);

    // ---- fp16 conversions ----
    convert_x_kernel<<<(NN * DD / 4 + 255) / 256, 256, 0, stream>>>(user_emb, item_emb, xh);
    convert_w_kernel<<<(2 * DD * DD + 255) / 256, 256, 0, stream>>>(W1, W2, Wt);

    // ---- Layer 1 ----
    aggregate_kernel<<<agg_blocks, 256, 0, stream>>>(edges, row_ptr, xh, u);
    gemm64_kernel<true><<<gemm_blocks, 256, 0, stream>>>(u, Wt, b1, (void*)xh);

    // ---- Layer 2 ----
    aggregate_kernel<<<agg_blocks, 256, 0, stream>>>(edges, row_ptr, xh, u);
    gemm64_kernel<false><<<gemm_blocks, 256, 0, stream>>>(u, Wt + DD * DD, b2, (void*)out);
}